// Round 3
// baseline (2134.112 us; speedup 1.0000x reference)
//
#include <hip/hip_runtime.h>

#define KDIM 50
#define TDIM 40
#define VDIM 30000
#define THDIM 800
#define EHDIM 200
#define EDIM 300
#define BDIM 100
#define DELTAF 0.005f
#define EPSF 1e-6f
#define LOGD (-5.2983174f)
#define MROWS 2560   // TDIM*64 rows for MFMA A operand
#define KPAD 320     // E padded to 320

typedef __attribute__((ext_vector_type(8))) short bf16x8;
typedef __attribute__((ext_vector_type(4))) float f32x4;
typedef unsigned int u32;

__device__ inline float wred64(float v) {
  v += __shfl_xor(v, 32, 64); v += __shfl_xor(v, 16, 64);
  v += __shfl_xor(v, 8, 64);  v += __shfl_xor(v, 4, 64);
  v += __shfl_xor(v, 2, 64);  v += __shfl_xor(v, 1, 64);
  return v;
}

__device__ inline unsigned short f2bf(float f) {
  union { float f; unsigned u; } x; x.f = f;
  unsigned r = x.u + 0x7fffu + ((x.u >> 16) & 1u);
  return (unsigned short)(r >> 16);
}

__device__ inline unsigned packbf(float a, float b) {
  return (unsigned)f2bf(a) | ((unsigned)f2bf(b) << 16);
}

__device__ inline void gload_lds16(const void* g, void* l) {
  __builtin_amdgcn_global_load_lds(
      (const __attribute__((address_space(1))) u32*)g,
      (__attribute__((address_space(3))) u32*)l, 16, 0, 0);
}

// ---------------- A2 prep: mu_q_alpha[k][t][e] -> bf16 A2[t*64+k][e<320] ----
__global__ void k_prep_A2(const float* __restrict__ mu_q, unsigned short* __restrict__ A2) {
  int idx = blockIdx.x * 256 + threadIdx.x;   // 2560*320 = 819200
  if (idx >= MROWS * KPAD) return;
  int m = idx / KPAD, e = idx % KPAD;
  int t = m >> 6, kp = m & 63;
  float v = 0.f;
  if (kp < KDIM && e < EDIM) v = mu_q[(kp * TDIM + t) * EDIM + e];
  A2[idx] = f2bf(v);
}

// ---------------- out_map partials: rnn_inp @ W_map^T -----------------------
// grid (64 v-chunks, 2 e-halves); register-persistent acc; NO atomics.
#define M3_CH 94
__global__ __launch_bounds__(256) void k_map3(const float* __restrict__ rnn,
                                              const float* __restrict__ Wmap,
                                              float* __restrict__ map_p) {
  __shared__ __align__(16) float rs[M3_CH * 44];
  __shared__ __align__(16) float wsb[M3_CH * 104];
  int vc = blockIdx.x, eh = blockIdx.y;
  int e0 = eh * 100, tid = threadIdx.x;
  float acc[4][4];
#pragma unroll
  for (int i = 0; i < 4; i++)
#pragma unroll
    for (int j = 0; j < 4; j++) acc[i][j] = 0.f;
  int eg = tid / 10, tg = tid % 10;
  for (int ch = 0; ch < 5; ch++) {
    int v0 = vc * 470 + ch * M3_CH;
    __syncthreads();
    for (int idx = tid; idx < TDIM * M3_CH; idx += 256) {
      int t = idx / M3_CH, vv = idx % M3_CH;
      int v = v0 + vv;
      rs[vv * 44 + t] = (v < VDIM) ? rnn[(size_t)t * VDIM + v] : 0.f;
    }
    for (int idx = tid; idx < 100 * M3_CH; idx += 256) {
      int e = idx / M3_CH, vv = idx % M3_CH;
      int v = v0 + vv;
      wsb[vv * 104 + e] = (v < VDIM) ? Wmap[(size_t)(e0 + e) * VDIM + v] : 0.f;
    }
    __syncthreads();
    if (tid < 250) {
      for (int vv = 0; vv < M3_CH; vv++) {
        float4 w4 = *(const float4*)&wsb[vv * 104 + eg * 4];
        float4 r4 = *(const float4*)&rs[vv * 44 + tg * 4];
        float wa[4] = {w4.x, w4.y, w4.z, w4.w};
        float ra[4] = {r4.x, r4.y, r4.z, r4.w};
#pragma unroll
        for (int i = 0; i < 4; i++)
#pragma unroll
          for (int j = 0; j < 4; j++) acc[i][j] += wa[i] * ra[j];
      }
    }
  }
  if (tid < 250) {
    size_t slice = (size_t)(eh * 64 + vc) * 4000;
#pragma unroll
    for (int i = 0; i < 4; i++)
#pragma unroll
      for (int j = 0; j < 4; j++)
        map_p[slice + (eg * 4 + i) * 40 + tg * 4 + j] = acc[i][j];
  }
}

__global__ void k_mapred(const float* __restrict__ map_p, const float* __restrict__ bmap,
                         float* __restrict__ omap) {
  int idx = blockIdx.x * 256 + threadIdx.x;
  if (idx >= TDIM * EHDIM) return;
  int t = idx / EHDIM, e = idx % EHDIM;
  int eh = e / 100, el = e % 100;
  float s = bmap[e];
  for (int vc = 0; vc < 64; vc++)
    s += map_p[(size_t)(eh * 64 + vc) * 4000 + el * 40 + t];
  omap[t * EHDIM + e] = s;
}

// ---------------- Whh transpose+pack to bf16 pairs: WhhT[l][jp][i] ----------
__global__ void k_wt(const float* __restrict__ Whh, unsigned* __restrict__ WhhT) {
  int l = blockIdx.x / 100, jp = blockIdx.x % 100;
  for (int i = threadIdx.x; i < THDIM; i += 256) {
    float w0 = Whh[(l * THDIM + i) * EHDIM + 2 * jp];
    float w1 = Whh[(l * THDIM + i) * EHDIM + 2 * jp + 1];
    WhhT[(l * 100 + jp) * THDIM + i] = packbf(w0, w1);
  }
}

// ---------------- LSTM input GEMM: G[t][i] = Wih[l][i]·x[t] + bih + bhh -----
__global__ void k_igemm(const float* __restrict__ Wih, const float* __restrict__ bih,
                        const float* __restrict__ bhh, const float* __restrict__ x,
                        float* __restrict__ G, int l) {
  int wave = threadIdx.x >> 6, lane = threadIdx.x & 63;
  int d0 = blockIdx.x * 80 + wave * 20;
  for (int n = 0; n < 20; n++) {
    int d = d0 + n;
    int t = d / THDIM, i = d % THDIM;
    const float* row = Wih + (l * THDIM + i) * EHDIM;
    const float* xt = x + t * EHDIM;
    float acc = 0.f;
#pragma unroll
    for (int m = 0; m < 4; m++) { int j = m * 64 + lane; if (j < EHDIM) acc += row[j] * xt[j]; }
    acc = wred64(acc);
    if (lane == 0) G[t * THDIM + i] = acc + bih[l * THDIM + i] + bhh[l * THDIM + i];
  }
}

// ---------------- LSTM recurrence (single block, streams bf16 WhhT) ---------
__global__ __launch_bounds__(1024) void k_rec(const unsigned* __restrict__ WT,
                                              const float* __restrict__ G,
                                              float* __restrict__ xout) {
  __shared__ __align__(16) float h[EHDIM];
  __shared__ float g[THDIM];
  int tid = threadIdx.x;
  if (tid < EHDIM) h[tid] = 0.f;
  float c = 0.f;
  __syncthreads();
  for (int t = 0; t < TDIM; t++) {
    if (tid < THDIM) {
      float acc = G[t * THDIM + tid];
      const unsigned* wp = WT + tid;
      const float4* h4 = (const float4*)h;
      for (int q = 0; q < 50; q++) {
        float4 hq = h4[q];
        unsigned wa = wp[(2 * q) * THDIM];
        unsigned wb = wp[(2 * q + 1) * THDIM];
        union { unsigned u; float f; } la, ha, lb, hb;
        la.u = wa << 16; ha.u = wa & 0xffff0000u;
        lb.u = wb << 16; hb.u = wb & 0xffff0000u;
        acc += la.f * hq.x + ha.f * hq.y + lb.f * hq.z + hb.f * hq.w;
      }
      g[tid] = acc;
    }
    __syncthreads();
    if (tid < EHDIM) {
      float si = 1.f / (1.f + __expf(-g[tid]));
      float sf = 1.f / (1.f + __expf(-g[200 + tid]));
      float sg = tanhf(g[400 + tid]);
      float so = 1.f / (1.f + __expf(-g[600 + tid]));
      c = sf * c + si * sg;
      float hn = so * tanhf(c);
      xout[t * EHDIM + tid] = hn;
      h[tid] = hn;
    }
    __syncthreads();
  }
}

// ---------------- eta chain (single block, W in LDS) ------------------------
#define WSTR 252
__global__ void k_eta(const float* __restrict__ Wmu, const float* __restrict__ bmu,
                      const float* __restrict__ Wls, const float* __restrict__ bls,
                      const float* __restrict__ lout, float* __restrict__ etas,
                      float* __restrict__ scal) {
  __shared__ __align__(16) float Wm[KDIM * WSTR + 4];
  __shared__ __align__(16) float Wl[KDIM * WSTR + 4];
  __shared__ __align__(16) float inp[256];
  __shared__ float mu_s[KDIM], ls_s[KDIM];
  int tid = threadIdx.x;  // 512
  for (int i = tid; i < KDIM * WSTR; i += 512) {
    int r = i / WSTR, c2 = i % WSTR;
    Wm[i] = (c2 < 250) ? Wmu[r * 250 + c2] : 0.f;
    Wl[i] = (c2 < 250) ? Wls[r * 250 + c2] : 0.f;
  }
  if (tid < 4) { Wm[KDIM * WSTR + tid] = 0.f; Wl[KDIM * WSTR + tid] = 0.f; }
  for (int i = tid; i < 256; i += 512) inp[i] = 0.f;
  __syncthreads();
  int wave = tid >> 6, lane = tid & 63;
  float kl = 0.f;
  for (int t = 0; t < TDIM; t++) {
    if (tid < EHDIM) inp[tid] = lout[t * EHDIM + tid];
    __syncthreads();
    float4 x4 = ((const float4*)inp)[lane];
    for (int jb = wave; jb < 2 * KDIM; jb += 8) {
      const float* Wrow = (jb < KDIM) ? (Wm + jb * WSTR) : (Wl + (jb - KDIM) * WSTR);
      float4 w4 = ((const float4*)Wrow)[lane];
      float acc = w4.x * x4.x + w4.y * x4.y + w4.z * x4.z + w4.w * x4.w;
      acc = wred64(acc);
      if (lane == 0) {
        if (jb < KDIM) mu_s[jb] = acc + bmu[jb];
        else ls_s[jb - KDIM] = acc + bls[jb - KDIM];
      }
    }
    __syncthreads();
    if (tid < 64) {
      float v = 0.f;
      if (tid < KDIM) {
        float m = mu_s[tid], ls = ls_s[tid];
        float ep = inp[EHDIM + tid];
        float d = m - ep;
        if (t == 0) v = 0.5f * ((__expf(ls) + d * d) / (1.f + EPSF) - 1.f - ls);
        else        v = 0.5f * ((__expf(ls) + d * d) / (DELTAF + EPSF) - 1.f + LOGD - ls);
        etas[t * KDIM + tid] = m;
      }
      v = wred64(v);
      if (tid == 0) kl += v;
    }
    __syncthreads();
    if (tid < KDIM) inp[EHDIM + tid] = mu_s[tid];
    __syncthreads();
  }
  if (tid == 0) scal[2] = kl;
}

// ---------------- h_pre partials (z=16 split-K, plain stores) ---------------
#define HP_BK 32
#define HP_STRIDE 132
__global__ __launch_bounds__(256, 2) void k_hpre(const float* __restrict__ nb,
                                                 const float* __restrict__ Wth,
                                                 float* __restrict__ hpre_p) {
  __shared__ __align__(16) float As[HP_BK * HP_STRIDE];
  __shared__ __align__(16) float Bs[HP_BK * HP_STRIDE];
  int tid = threadIdx.x;
  int nt = blockIdx.x, zc = blockIdx.y;
  int kt0 = zc * 59, ktend = min(938, kt0 + 59);
  float acc[8][8];
#pragma unroll
  for (int i = 0; i < 8; i++)
#pragma unroll
    for (int j = 0; j < 8; j++) acc[i][j] = 0.f;
  int tx = tid & 15, ty = tid >> 4;
  for (int kt = kt0; kt < ktend; kt++) {
    int v0 = kt * HP_BK;
#pragma unroll
    for (int r = 0; r < 4; r++) {
      int j = tid + r * 256;
      int row = j >> 3, c4 = (j & 7) * 4;
      int v = v0 + c4;
      float4 val = {0.f, 0.f, 0.f, 0.f};
      if (row < BDIM) {
        const float* base = nb + (size_t)row * VDIM + v;
        if (v + 3 < VDIM) val = *(const float4*)base;
        else {
          if (v < VDIM) val.x = base[0];
          if (v + 1 < VDIM) val.y = base[1];
          if (v + 2 < VDIM) val.z = base[2];
        }
      }
      As[(c4 + 0) * HP_STRIDE + row] = val.x;
      As[(c4 + 1) * HP_STRIDE + row] = val.y;
      As[(c4 + 2) * HP_STRIDE + row] = val.z;
      As[(c4 + 3) * HP_STRIDE + row] = val.w;
    }
#pragma unroll
    for (int r = 0; r < 4; r++) {
      int j = tid + r * 256;
      int row = j >> 3, c4 = (j & 7) * 4;
      int th = nt * 128 + row;
      int v = v0 + c4;
      float4 val = {0.f, 0.f, 0.f, 0.f};
      if (th < THDIM) {
        const float* base = Wth + (size_t)th * 30050 + v;
        if (v + 3 < VDIM) {
          float2 p0 = *(const float2*)base;
          float2 p1 = *(const float2*)(base + 2);
          val.x = p0.x; val.y = p0.y; val.z = p1.x; val.w = p1.y;
        } else {
          if (v < VDIM) val.x = base[0];
          if (v + 1 < VDIM) val.y = base[1];
          if (v + 2 < VDIM) val.z = base[2];
        }
      }
      Bs[(c4 + 0) * HP_STRIDE + row] = val.x;
      Bs[(c4 + 1) * HP_STRIDE + row] = val.y;
      Bs[(c4 + 2) * HP_STRIDE + row] = val.z;
      Bs[(c4 + 3) * HP_STRIDE + row] = val.w;
    }
    __syncthreads();
#pragma unroll
    for (int k = 0; k < HP_BK; k++) {
      float4 a0 = *(const float4*)&As[k * HP_STRIDE + ty * 8];
      float4 a1 = *(const float4*)&As[k * HP_STRIDE + ty * 8 + 4];
      float4 b0 = *(const float4*)&Bs[k * HP_STRIDE + tx * 8];
      float4 b1 = *(const float4*)&Bs[k * HP_STRIDE + tx * 8 + 4];
      float a[8] = {a0.x, a0.y, a0.z, a0.w, a1.x, a1.y, a1.z, a1.w};
      float b[8] = {b0.x, b0.y, b0.z, b0.w, b1.x, b1.y, b1.z, b1.w};
#pragma unroll
      for (int i = 0; i < 8; i++)
#pragma unroll
        for (int j = 0; j < 8; j++) acc[i][j] += a[i] * b[j];
    }
    __syncthreads();
  }
#pragma unroll
  for (int i = 0; i < 8; i++) {
    int bb = ty * 8 + i;
    if (bb >= BDIM) continue;
#pragma unroll
    for (int j = 0; j < 8; j++) {
      int th = nt * 128 + tx * 8 + j;
      if (th < THDIM) hpre_p[(size_t)zc * 80000 + bb * THDIM + th] = acc[i][j];
    }
  }
}

// ---------------- theta path: tanh, softmax, kl_theta -----------------------
__global__ void k_theta(const float* __restrict__ hpre_p, const float* __restrict__ bth,
                        const float* __restrict__ Wth, const float* __restrict__ Wmt,
                        const float* __restrict__ bmt, const float* __restrict__ Wlt,
                        const float* __restrict__ blt, const float* __restrict__ etas,
                        const int* __restrict__ times, float* __restrict__ theta,
                        float* __restrict__ scal) {
  __shared__ float et[KDIM];
  __shared__ float hl[THDIM];
  __shared__ float mu_s[KDIM], ls_s[KDIM];
  int b = blockIdx.x, tid = threadIdx.x;
  if (tid < KDIM) et[tid] = etas[times[b] * KDIM + tid];
  __syncthreads();
  for (int th = tid; th < THDIM; th += 256) {
    float acc = bth[th];
#pragma unroll
    for (int z = 0; z < 16; z++) acc += hpre_p[(size_t)z * 80000 + b * THDIM + th];
    const float* wrow = Wth + (size_t)th * 30050 + VDIM;
#pragma unroll 10
    for (int k = 0; k < KDIM; k++) acc += et[k] * wrow[k];
    hl[th] = tanhf(acc);
  }
  __syncthreads();
  int wave = tid >> 6, lane = tid & 63;
  for (int jb = wave; jb < 2 * KDIM; jb += 4) {
    const float* row = (jb < KDIM) ? (Wmt + jb * THDIM) : (Wlt + (jb - KDIM) * THDIM);
    float acc = 0.f;
#pragma unroll
    for (int m = 0; m < 13; m++) { int j = m * 64 + lane; if (j < THDIM) acc += row[j] * hl[j]; }
    acc = wred64(acc);
    if (lane == 0) {
      if (jb < KDIM) mu_s[jb] = acc + bmt[jb];
      else ls_s[jb - KDIM] = acc + blt[jb - KDIM];
    }
  }
  __syncthreads();
  if (tid < 64) {
    float m = (tid < KDIM) ? mu_s[tid] : -1e30f;
    float mx = m;
#pragma unroll
    for (int o = 32; o >= 1; o >>= 1) mx = fmaxf(mx, __shfl_xor(mx, o, 64));
    float e = (tid < KDIM) ? __expf(m - mx) : 0.f;
    float s = wred64(e);
    if (tid < KDIM) theta[b * KDIM + tid] = e / s;
    float v = 0.f;
    if (tid < KDIM) {
      float ls = ls_s[tid];
      float d = mu_s[tid] - et[tid];
      v = 0.5f * ((__expf(ls) + d * d) / (1.f + EPSF) - 1.f - ls);
    }
    v = wred64(v);
    if (tid == 0) atomicAdd(&scal[3], v);
  }
}

// ---------------- kl_alpha ---------------------------------------------------
__global__ void k_klalpha(const float* __restrict__ mu, const float* __restrict__ ls,
                          float* __restrict__ scal) {
  int idx = blockIdx.x * 256 + threadIdx.x;
  float v = 0.f;
  if (idx < KDIM * TDIM * EDIM) {
    int t = (idx / EDIM) % TDIM;
    float l = ls[idx], m = mu[idx];
    if (t == 0) v = 0.5f * ((__expf(l) + m * m) / (1.f + EPSF) - 1.f - l);
    else { float d = m - mu[idx - EDIM]; v = 0.5f * ((__expf(l) + d * d) / (DELTAF + EPSF) - 1.f + LOGD - l); }
  }
  v = wred64(v);
  __shared__ float p[4];
  if ((threadIdx.x & 63) == 0) p[threadIdx.x >> 6] = v;
  __syncthreads();
  if (threadIdx.x == 0) atomicAdd(&scal[1], p[0] + p[1] + p[2] + p[3]);
}

// ---------------- time buckets ----------------------------------------------
__global__ void k_bucket(const int* __restrict__ times, int* __restrict__ bcnt,
                         int* __restrict__ bucket) {
  __shared__ int cnt[TDIM];
  int tid = threadIdx.x;  // 128
  if (tid < TDIM) cnt[tid] = 0;
  __syncthreads();
  if (tid < BDIM) {
    int t = times[tid];
    int s = atomicAdd(&cnt[t], 1);
    bucket[t * 128 + s] = tid;
  }
  __syncthreads();
  if (tid < TDIM) bcnt[tid] = cnt[tid];
}

// ---------------- wgt[b][k] = theta[b][k] / Z[t_b*64+k] ---------------------
__global__ void k_wgt(const float* __restrict__ theta, const float* __restrict__ Z,
                      const int* __restrict__ times, float* __restrict__ wgt) {
  int idx = blockIdx.x * 256 + threadIdx.x;  // 6400
  if (idx >= BDIM * 64) return;
  int b = idx >> 6, k = idx & 63;
  float v = 0.f;
  if (k < KDIM) v = theta[b * KDIM + k] / Z[times[b] * 64 + k];
  wgt[idx] = v;
}

// ================= B-resident MFMA GEMM (both passes) =======================
// grid = 235 v-tiles; B (128x320 bf16) staged once, slot-swizzled;
// loop 20 m-tiles with double-buffered A slices (BK=64) via global_load_lds.
template <bool PASSB>
__global__ __launch_bounds__(256) void k_gemm(
    const unsigned short* __restrict__ A2, const float* __restrict__ wemb,
    float* __restrict__ Zp, const float* __restrict__ wgt,
    const float* __restrict__ bows, const int* __restrict__ bcnt,
    const int* __restrict__ bucket, float* __restrict__ scal) {
  __shared__ __align__(16) unsigned short Bs[128 * 320];
  __shared__ __align__(16) unsigned short As[2][128 * 64];
  __shared__ float Zacc[MROWS];
  __shared__ float p[4];
  int tid = threadIdx.x, wv = tid >> 6, lane = tid & 63;
  int r15 = lane & 15, gh = lane >> 4;
  int vbase = blockIdx.x * 128;

  // ---- stage B tile: fp32 -> bf16, 16B-slot XOR swizzle, zero pad ----
  for (int idx = tid; idx < 128 * 80; idx += 256) {
    int vp = idx / 80, e4 = (idx % 80) * 4;
    int v = vbase + vp;
    float4 w = {0.f, 0.f, 0.f, 0.f};
    if (v < VDIM && e4 < EDIM) w = *(const float4*)(wemb + (size_t)v * EDIM + e4);
    int slot = e4 >> 3;
    int phys = slot ^ (vp & 7);
    unsigned* dst = (unsigned*)(Bs + vp * 320 + phys * 8 + (e4 & 4));
    dst[0] = packbf(w.x, w.y);
    dst[1] = packbf(w.z, w.w);
  }
  if (!PASSB)
    for (int i = tid; i < MROWS; i += 256) Zacc[i] = 0.f;

  auto stageA = [&](int mt, int kt, int b) {
    const unsigned short* src = A2 + (size_t)mt * 128 * KPAD + kt * 64;
    unsigned short* dstb = As[b];
#pragma unroll
    for (int j = 0; j < 4; j++) {
      int rowl = wv * 32 + j * 8 + (lane >> 3);
      int log = (lane & 7) ^ (rowl & 7);
      gload_lds16(src + (size_t)rowl * KPAD + log * 8,
                  dstb + (wv * 32 + j * 8) * 64);
    }
  };

  f32x4 acc[4][4];
  float nacc = 0.f;
  stageA(0, 0, 0);
  int buf = 0;
  for (int mt = 0; mt < 20; mt++) {
#pragma unroll
    for (int i = 0; i < 4; i++)
#pragma unroll
      for (int j = 0; j < 4; j++) acc[i][j] = (f32x4){0.f, 0.f, 0.f, 0.f};
    for (int kt = 0; kt < 5; kt++) {
      int nk = kt + 1, nm = mt;
      if (nk == 5) { nk = 0; nm++; }
      if (nm < 20) stageA(nm, nk, buf ^ 1);
      __syncthreads();
      const unsigned short* Ab = As[buf];
#pragma unroll
      for (int k2 = 0; k2 < 2; k2++) {
        bf16x8 af[4], bfr[4];
        int sl = k2 * 4 + gh;
        int physA = sl ^ (r15 & 7);
        int physB = (kt * 8 + sl) ^ (r15 & 7);
#pragma unroll
        for (int s = 0; s < 4; s++) {
          int ra = (wv >> 1) * 64 + s * 16 + r15;
          af[s] = *(const bf16x8*)(Ab + ra * 64 + physA * 8);
          int rb = (wv & 1) * 64 + s * 16 + r15;
          bfr[s] = *(const bf16x8*)(Bs + rb * 320 + physB * 8);
        }
#pragma unroll
        for (int si = 0; si < 4; si++)
#pragma unroll
          for (int sj = 0; sj < 4; sj++)
            acc[si][sj] = __builtin_amdgcn_mfma_f32_16x16x32_bf16(af[si], bfr[sj], acc[si][sj], 0, 0, 0);
      }
      __syncthreads();
      buf ^= 1;
    }
    // ---- per-m-tile epilogue ----
    if (!PASSB) {
#pragma unroll
      for (int si = 0; si < 4; si++) {
#pragma unroll
        for (int r = 0; r < 4; r++) {
          float es = 0.f;
#pragma unroll
          for (int sj = 0; sj < 4; sj++) {
            int v = vbase + (wv & 1) * 64 + sj * 16 + r15;
            if (v < VDIM) es += __expf(acc[si][sj][r]);
          }
          es += __shfl_xor(es, 1, 64); es += __shfl_xor(es, 2, 64);
          es += __shfl_xor(es, 4, 64); es += __shfl_xor(es, 8, 64);
          if (r15 == 0)
            atomicAdd(&Zacc[mt * 128 + (wv >> 1) * 64 + si * 16 + gh * 4 + r], es);
        }
      }
    } else {
#pragma unroll
      for (int si = 0; si < 4; si++)
#pragma unroll
        for (int sj = 0; sj < 4; sj++)
#pragma unroll
          for (int r = 0; r < 4; r++) acc[si][sj][r] = __expf(acc[si][sj][r]);
      int t = mt * 2 + (wv >> 1);
      int cnt = bcnt[t];
      for (int n = 0; n < cnt; n++) {
        int b = bucket[t * 128 + n];
        float4 w4[4];
#pragma unroll
        for (int si = 0; si < 4; si++)
          w4[si] = *(const float4*)(wgt + b * 64 + si * 16 + gh * 4);
#pragma unroll
        for (int sj = 0; sj < 4; sj++) {
          float local = 0.f;
#pragma unroll
          for (int si = 0; si < 4; si++)
            local += w4[si].x * acc[si][sj][0] + w4[si].y * acc[si][sj][1] +
                     w4[si].z * acc[si][sj][2] + w4[si].w * acc[si][sj][3];
          local += __shfl_xor(local, 16, 64);
          local += __shfl_xor(local, 32, 64);
          int v = vbase + (wv & 1) * 64 + sj * 16 + r15;
          if (lane < 16 && v < VDIM)
            nacc += bows[(size_t)b * VDIM + v] * __logf(local + EPSF);
        }
      }
    }
  }
  if (!PASSB) {
    __syncthreads();
    for (int i = tid; i < MROWS; i += 256)
      Zp[(size_t)blockIdx.x * MROWS + i] = Zacc[i];
  } else {
    nacc = wred64(nacc);
    if (lane == 0) p[wv] = nacc;
    __syncthreads();
    if (tid == 0) atomicAdd(&scal[0], p[0] + p[1] + p[2] + p[3]);
  }
}

// ---------------- Z reduce: Z[i] = sum over 235 v-blocks --------------------
__global__ void k_zred(const float* __restrict__ Zp, float* __restrict__ Z) {
  int i = blockIdx.x * 256 + threadIdx.x;
  if (i >= MROWS) return;
  float s = 0.f;
  for (int b = 0; b < 235; b++) s += Zp[(size_t)b * MROWS + i];
  Z[i] = s;
}

// ---------------- finalize ---------------------------------------------------
__global__ void k_finalize(const float* __restrict__ scal, float* __restrict__ out) {
  if (threadIdx.x == 0 && blockIdx.x == 0) {
    float nll = -scal[0];
    out[0] = nll + scal[1] + scal[2] + scal[3];
    out[1] = nll;
    out[2] = scal[1];
    out[3] = scal[2];
    out[4] = scal[3];
  }
}

extern "C" void kernel_launch(void* const* d_in, const int* in_sizes, int n_in,
                              void* d_out, int out_size, void* d_ws, size_t ws_size,
                              hipStream_t stream) {
  const float* bows  = (const float*)d_in[0];
  const float* nbows = (const float*)d_in[1];
  const float* rnn   = (const float*)d_in[2];
  const float* wemb  = (const float*)d_in[3];
  const float* mua   = (const float*)d_in[4];
  const float* lsa   = (const float*)d_in[5];
  const float* Wth   = (const float*)d_in[6];
  const float* bth   = (const float*)d_in[7];
  const float* Wmt   = (const float*)d_in[8];
  const float* bmt   = (const float*)d_in[9];
  const float* Wlt   = (const float*)d_in[10];
  const float* blt   = (const float*)d_in[11];
  const float* Wmap  = (const float*)d_in[12];
  const float* bmap  = (const float*)d_in[13];
  const float* Wih   = (const float*)d_in[14];
  const float* Whh   = (const float*)d_in[15];
  const float* bihp  = (const float*)d_in[16];
  const float* bhhp  = (const float*)d_in[17];
  const float* Wme   = (const float*)d_in[18];
  const float* bme   = (const float*)d_in[19];
  const float* Wle   = (const float*)d_in[20];
  const float* ble   = (const float*)d_in[21];
  const int* times   = (const int*)d_in[22];

  float* ws = (float*)d_ws;
  float* scal   = ws;                  // 8
  float* Z      = ws + 8;              // 2560
  float* omap   = ws + 2568;           // 8000
  float* xa     = ws + 10568;          // 8000
  float* xb     = ws + 18568;          // 8000
  float* lout   = ws + 26568;          // 8000
  float* Gin    = ws + 34568;          // 32000
  unsigned* WhhT = (unsigned*)(ws + 66568);    // 240000
  float* etas   = ws + 306568;         // 2000
  float* theta  = ws + 308568;         // 5000
  float* wgt    = ws + 313568;         // 6400
  int* bcnt     = (int*)(ws + 319968); // 64
  int* bucket   = (int*)(ws + 320032); // 5120
  unsigned short* A2 = (unsigned short*)(ws + 325152);  // 819200 ushorts
  float* hpre_p = ws + 734752;         // 16*80000 = 1280000
  float* map_p  = ws + 2014752;        // 128*4000 = 512000
  float* Zp     = ws + 2526752;        // 235*2560 = 601600 -> end 3128352 (12.5 MB)

  hipMemsetAsync(ws, 0, 32, stream);   // scal only

  k_prep_A2<<<3200, 256, 0, stream>>>(mua, A2);
  k_map3<<<dim3(64, 2), 256, 0, stream>>>(rnn, Wmap, map_p);
  k_mapred<<<32, 256, 0, stream>>>(map_p, bmap, omap);
  k_wt<<<300, 256, 0, stream>>>(Whh, WhhT);
  k_bucket<<<1, 128, 0, stream>>>(times, bcnt, bucket);

  k_gemm<false><<<235, 256, 0, stream>>>(A2, wemb, Zp, nullptr, nullptr,
                                         nullptr, nullptr, nullptr);
  k_zred<<<10, 256, 0, stream>>>(Zp, Z);

  k_igemm<<<400, 256, 0, stream>>>(Wih, bihp, bhhp, omap, Gin, 0);
  k_rec<<<1, 1024, 0, stream>>>(WhhT, Gin, xa);
  k_igemm<<<400, 256, 0, stream>>>(Wih, bihp, bhhp, xa, Gin, 1);
  k_rec<<<1, 1024, 0, stream>>>(WhhT + 100 * 800, Gin, xb);
  k_igemm<<<400, 256, 0, stream>>>(Wih, bihp, bhhp, xb, Gin, 2);
  k_rec<<<1, 1024, 0, stream>>>(WhhT + 200 * 800, Gin, lout);

  k_eta<<<1, 512, 0, stream>>>(Wme, bme, Wle, ble, lout, etas, scal);
  k_hpre<<<dim3(7, 16), 256, 0, stream>>>(nbows, Wth, hpre_p);
  k_theta<<<100, 256, 0, stream>>>(hpre_p, bth, Wth, Wmt, bmt, Wlt, blt, etas, times, theta, scal);
  k_wgt<<<25, 256, 0, stream>>>(theta, Z, times, wgt);
  k_klalpha<<<2344, 256, 0, stream>>>(mua, lsa, scal);

  k_gemm<true><<<235, 256, 0, stream>>>(A2, wemb, nullptr, wgt, bows, bcnt,
                                        bucket, scal);
  k_finalize<<<1, 64, 0, stream>>>(scal, (float*)d_out);
}